// Round 17
// baseline (390.366 us; speedup 1.0000x reference)
//
#include <hip/hip_runtime.h>
#include <math.h>

#define N_NODES 100000
#define N_EDGES 1600000
#define HEADS 4
#define NBKT ((N_NODES + 255) / 256)
#define CHUNK_E 4096
#define NCHUNK ((N_EDGES + CHUNK_E - 1) / CHUNK_E)
#define GN ((N_NODES + 255) / 256)
#define SUM_ROWS 16
#define NRB ((NCHUNK + SUM_ROWS - 1) / SUM_ROWS)

typedef unsigned short ushort_t;
typedef unsigned char  uchar_t;

__device__ __forceinline__ ushort_t f2bf(float x) {
    unsigned u = __float_as_uint(x);
    u += 0x7FFF + ((u >> 16) & 1);
    return (ushort_t)(u >> 16);
}
__device__ __forceinline__ float bf2f(ushort_t v) {
    return __uint_as_float(((unsigned)v) << 16);
}
__device__ __forceinline__ void unpack2(unsigned u, float& lo, float& hi) {
    lo = __uint_as_float(u << 16);
    hi = __uint_as_float(u & 0xffff0000u);
}
// unsigned e5m3 fp8 (ReLU outputs only)
__device__ __forceinline__ uchar_t f2fp8(float x) {
    if (x <= 0.0f) return 0;
    unsigned u = __float_as_uint(x) + (1u << 19);
    int e = (int)(u >> 23) - 127 + 15;
    if (e <= 0) return 0;
    if (e > 31) return (uchar_t)255;
    return (uchar_t)((e << 3) | ((u >> 20) & 7));
}
__device__ __forceinline__ float fp8d(uchar_t b) {
    unsigned v = (((unsigned)(b >> 3) + 112u) << 23) | ((unsigned)(b & 7) << 20);
    return (b == 0) ? 0.0f : __uint_as_float(v);
}

// ---------------- K1: per-chunk histogram rows + p1/x->bf16 + bucket_cnt zero ----

__global__ __launch_bounds__(256) void bhist_pcast_kernel(
        const int* __restrict__ dst, int* __restrict__ hist_rows,
        const float* __restrict__ x, const float* __restrict__ U,
        float* __restrict__ p, ushort_t* __restrict__ xbf,
        int* __restrict__ bucket_cnt)
{
    __shared__ int h[NBKT];
    if (blockIdx.x < NCHUNK) {
        for (int i = threadIdx.x; i < NBKT; i += 256) h[i] = 0;
        __syncthreads();
        int base = blockIdx.x * CHUNK_E;
        #pragma unroll
        for (int j = 0; j < CHUNK_E / 256; j++) {
            int e = base + j * 256 + threadIdx.x;
            if (e < N_EDGES) atomicAdd(&h[dst[e] >> 8], 1);
        }
        __syncthreads();
        for (int i = threadIdx.x; i < NBKT; i += 256)
            hist_rows[(size_t)blockIdx.x * NBKT + i] = h[i];
    } else if (blockIdx.x < NCHUNK + GN) {
        int n = (blockIdx.x - NCHUNK) * 256 + threadIdx.x;
        if (n >= N_NODES) return;
        float a0 = 0, a1 = 0, a2 = 0, a3 = 0;
        const float* hr = x + (size_t)n * 16;
        float xv[16];
        #pragma unroll
        for (int f = 0; f < 16; f++) {
            xv[f] = hr[f];
            a0 += xv[f] * U[f * 4 + 0];
            a1 += xv[f] * U[f * 4 + 1];
            a2 += xv[f] * U[f * 4 + 2];
            a3 += xv[f] * U[f * 4 + 3];
        }
        *(float4*)(p + (size_t)n * 4) = make_float4(a0, a1, a2, a3);
        #pragma unroll
        for (int j = 0; j < 4; j++) {
            ushort4 u;
            u.x = f2bf(xv[4 * j + 0]); u.y = f2bf(xv[4 * j + 1]);
            u.z = f2bf(xv[4 * j + 2]); u.w = f2bf(xv[4 * j + 3]);
            *(ushort4*)(xbf + (size_t)n * 16 + 4 * j) = u;
        }
    } else {
        for (int i = threadIdx.x; i < NBKT; i += 256) bucket_cnt[i] = 0;
    }
}

// ---------------- K2a: parallel column-sum ----

__global__ __launch_bounds__(256) void ksum_kernel(const int* __restrict__ hist_rows,
                                                   int* __restrict__ bucket_cnt) {
    int r0 = blockIdx.x * SUM_ROWS;
    int r1 = min(r0 + SUM_ROWS, NCHUNK);
    for (int i = threadIdx.x; i < NBKT; i += 256) {
        int v = 0;
        for (int r = r0; r < r1; r++) v += hist_rows[(size_t)r * NBKT + i];
        if (v) atomicAdd(&bucket_cnt[i], v);
    }
}

// ---------------- K2b: exclusive scan -> base + cursor ----

__global__ __launch_bounds__(512) void bscan_kernel(const int* __restrict__ bucket_cnt,
                                                    int* __restrict__ bucket_base,
                                                    int* __restrict__ bucket_cursor) {
    __shared__ int tmp[512];
    int i = threadIdx.x;
    int v = (i < NBKT) ? bucket_cnt[i] : 0;
    tmp[i] = v;
    __syncthreads();
    for (int off = 1; off < 512; off <<= 1) {
        int t = (i >= off) ? tmp[i - off] : 0;
        __syncthreads();
        tmp[i] += t;
        __syncthreads();
    }
    int excl = tmp[i] - v;
    if (i < NBKT) { bucket_base[i] = excl; bucket_cursor[i] = excl; }
    if (i == NBKT) bucket_base[NBKT] = N_EDGES;
}

// ---------------- K3: partition into coarse buckets; packed = (dst&255)<<20 | src ----

__global__ __launch_bounds__(256) void partition_kernel(const int* __restrict__ src,
                                                        const int* __restrict__ dst,
                                                        int* __restrict__ bucket_cursor,
                                                        int* __restrict__ csr_tmp) {
    constexpr int EPT = CHUNK_E / 256;
    __shared__ int h[NBKT];
    __shared__ int gbase[NBKT];
    __shared__ int rcnt[NBKT];
    for (int i = threadIdx.x; i < NBKT; i += 256) { h[i] = 0; rcnt[i] = 0; }
    __syncthreads();
    int base = blockIdx.x * CHUNK_E;
    int d[EPT], s[EPT];
    #pragma unroll
    for (int j = 0; j < EPT; j++) {
        int e = base + j * 256 + threadIdx.x;
        d[j] = (e < N_EDGES) ? dst[e] : -1;
        s[j] = (e < N_EDGES) ? src[e] : 0;
        if (d[j] >= 0) atomicAdd(&h[d[j] >> 8], 1);
    }
    __syncthreads();
    for (int i = threadIdx.x; i < NBKT; i += 256)
        if (h[i]) gbase[i] = atomicAdd(&bucket_cursor[i], h[i]);
    __syncthreads();
    #pragma unroll
    for (int j = 0; j < EPT; j++) {
        if (d[j] >= 0) {
            int b = d[j] >> 8;
            int r = atomicAdd(&rcnt[b], 1);
            csr_tmp[gbase[b] + r] = ((d[j] & 255) << 20) | s[j];
        }
    }
}

// ---------------- K4: per-bucket build; csr_src keeps dlow packed ----

__global__ __launch_bounds__(256) void bucket_build_kernel(const int* __restrict__ bucket_base,
                                                           const int* __restrict__ csr_tmp,
                                                           int* __restrict__ rowptr,
                                                           int* __restrict__ csr_src) {
    __shared__ int cnt[256];
    __shared__ int tscan[256];
    __shared__ int exc[256];
    __shared__ int stage[8192];
    int b = blockIdx.x;
    int rbeg = bucket_base[b], rend = bucket_base[b + 1];
    int sz = rend - rbeg;
    int tid = threadIdx.x;

    cnt[tid] = 0;
    __syncthreads();
    for (int k = rbeg + tid; k < rend; k += 256) atomicAdd(&cnt[csr_tmp[k] >> 20], 1);
    __syncthreads();
    int v = cnt[tid];
    tscan[tid] = v;
    __syncthreads();
    for (int off = 1; off < 256; off <<= 1) {
        int t = (tid >= off) ? tscan[tid - off] : 0;
        __syncthreads();
        tscan[tid] += t;
        __syncthreads();
    }
    int ex = tscan[tid] - v;
    int node = b * 256 + tid;
    if (node < N_NODES) rowptr[node] = rbeg + ex;
    if (b == 0 && tid == 0) rowptr[N_NODES] = N_EDGES;
    exc[tid] = ex;
    cnt[tid] = 0;
    __syncthreads();

    if (sz <= 8192) {
        for (int k = rbeg + tid; k < rend; k += 256) {
            int pk = csr_tmp[k];
            int dl = pk >> 20;
            int r  = atomicAdd(&cnt[dl], 1);
            stage[exc[dl] + r] = pk;
        }
        __syncthreads();
        for (int i = tid; i < sz; i += 256) csr_src[rbeg + i] = stage[i];
    } else {
        for (int k = rbeg + tid; k < rend; k += 256) {
            int pk = csr_tmp[k];
            int dl = pk >> 20;
            int r  = atomicAdd(&cnt[dl], 1);
            csr_src[rbeg + exc[dl] + r] = pk;
        }
    }
}

// ---------------- fused conv (conv1/conv2): gather -> LDS ztile -> in-LDS GEMM
// -> bf16/fp8 out + p_next.  IN_FMT 0=bf16.  OUT_FP8 selects output encoding.
// W is LDS-resident (4/8 KB), amortized over NPB=64 nodes (fixes R12's failure).

template<int FIN, int FOUT, int OUT_FP8>
__global__ __launch_bounds__(256) void conv_fused_kernel(
        const int* __restrict__ rowptr, const int* __restrict__ csr_src,
        const float* __restrict__ p, const float* __restrict__ cvec,
        const ushort_t* __restrict__ hprev,   // [N, FIN] bf16
        const float* __restrict__ W,          // [FIN, 4*FOUT]
        const float* __restrict__ b,          // [FOUT]
        ushort_t* __restrict__ out_bf,        // [N, FOUT] (OUT_FP8==0)
        uchar_t* __restrict__ out_f8,         // [N, FOUT] (OUT_FP8==1)
        const float* __restrict__ Unext,      // [FOUT,4]
        float* __restrict__ pnext)            // [N,4]
{
    constexpr int LPN   = FIN / 4;            // 4
    constexpr int NPB   = 256 / LPN;          // 64
    constexpr int CHUNK = 1024;
    constexpr int K     = 4 * FIN;            // 64
    constexpr int ZK    = K + 4;              // padded ztile stride (16B-aligned)
    constexpr int HS    = FOUT + 1;           // hout stride (scalar stores)
    constexpr int WSZ   = K * FOUT;
    constexpr int UNION_A = CHUNK * 16 + CHUNK * 4;          // qs + ssrc
    constexpr int UNION_B = NPB * ZK * 4 + NPB * HS * 4;     // ztile + hout
    constexpr int UNION   = UNION_A > UNION_B ? UNION_A : UNION_B;

    __shared__ int    sbeg[NPB + 1];
    __shared__ float4 pds[NPB];
    __shared__ float  Ws[WSZ];
    __shared__ float  Uloc[FOUT * 4];
    __shared__ __align__(16) char ubuf[UNION];
    float4* qs    = (float4*)ubuf;
    int*    ssrc  = (int*)(ubuf + CHUNK * 16);
    float*  ztile = (float*)ubuf;
    float*  hout  = (float*)(ubuf + NPB * ZK * 4);

    int tid  = threadIdx.x;
    int nloc = tid / LPN;
    int fl   = (tid - nloc * LPN) * 4;
    int n0   = blockIdx.x * NPB;
    int n    = n0 + nloc;
    int dbase = n0 & 255;

    for (int i = tid; i <= NPB; i += 256) {
        int idx = n0 + i;
        sbeg[i] = rowptr[idx > N_NODES ? N_NODES : idx];
    }
    for (int i = tid; i < NPB; i += 256) {
        int idx = n0 + i;
        pds[i] = *(const float4*)(p + (size_t)(idx < N_NODES ? idx : N_NODES - 1) * 4);
    }
    // load W permuted k-major: Ws[(h*FIN+f)*FOUT+o] = W[f*4*FOUT + h*FOUT + o]
    for (int i = tid; i < WSZ; i += 256) {
        int f = i / (4 * FOUT);
        int r = i - f * (4 * FOUT);
        int h = r / FOUT;
        int o = r - h * FOUT;
        Ws[(h * FIN + f) * FOUT + o] = W[i];
    }
    for (int i = tid; i < FOUT * 4; i += 256) Uloc[i] = Unext[i];
    float c0 = cvec[0], c1 = cvec[1], c2 = cvec[2], c3 = cvec[3];
    __syncthreads();

    int BB = sbeg[0], BE = sbeg[NPB];
    int beg = sbeg[nloc], end = sbeg[nloc + 1];

    float4 acc0 = make_float4(0, 0, 0, 0), acc1 = acc0, acc2 = acc0, acc3 = acc0;

    // ---- phase A: gather ----
    for (int cbase = BB; cbase < BE; cbase += CHUNK) {
        int cend = min(cbase + CHUNK, BE);
        __syncthreads();
        for (int k = cbase + tid; k < cend; k += 256) {
            int pk = csr_src[k];
            int s  = pk & ((1 << 20) - 1);
            int nl = (pk >> 20) - dbase;
            float4 ps = *(const float4*)(p + (size_t)s * 4);
            float4 pd = pds[nl];
            float l0 = ps.x - pd.x + c0;
            float l1 = ps.y - pd.y + c1;
            float l2 = ps.z - pd.z + c2;
            float l3 = ps.w - pd.w + c3;
            float m  = fmaxf(fmaxf(l0, l1), fmaxf(l2, l3));
            float e0 = __expf(l0 - m), e1 = __expf(l1 - m);
            float e2 = __expf(l2 - m), e3 = __expf(l3 - m);
            float deg = (float)(sbeg[nl + 1] - sbeg[nl]);
            float inv = 1.0f / (fmaxf(deg, 1.0f) * (e0 + e1 + e2 + e3));
            qs[k - cbase]   = make_float4(e0 * inv, e1 * inv, e2 * inv, e3 * inv);
            ssrc[k - cbase] = s;
        }
        __syncthreads();
        int kb = (beg > cbase ? beg : cbase) - cbase;
        int ke = (end < cend ? end : cend) - cbase;
        int k = kb;
        for (; k + 4 <= ke; k += 4) {
            uint2 r[4];
            #pragma unroll
            for (int j = 0; j < 4; j++)
                r[j] = *(const uint2*)(hprev + (size_t)ssrc[k + j] * FIN + fl);
            float xv[4][4];
            #pragma unroll
            for (int j = 0; j < 4; j++) {
                unpack2(r[j].x, xv[j][0], xv[j][1]);
                unpack2(r[j].y, xv[j][2], xv[j][3]);
            }
            #pragma unroll
            for (int j = 0; j < 4; j++) {
                float4 q = qs[k + j];
                acc0.x += q.x * xv[j][0]; acc0.y += q.x * xv[j][1];
                acc0.z += q.x * xv[j][2]; acc0.w += q.x * xv[j][3];
                acc1.x += q.y * xv[j][0]; acc1.y += q.y * xv[j][1];
                acc1.z += q.y * xv[j][2]; acc1.w += q.y * xv[j][3];
                acc2.x += q.z * xv[j][0]; acc2.y += q.z * xv[j][1];
                acc2.z += q.z * xv[j][2]; acc2.w += q.z * xv[j][3];
                acc3.x += q.w * xv[j][0]; acc3.y += q.w * xv[j][1];
                acc3.z += q.w * xv[j][2]; acc3.w += q.w * xv[j][3];
            }
        }
        for (; k < ke; k++) {
            float x0, x1, x2, x3;
            uint2 r = *(const uint2*)(hprev + (size_t)ssrc[k] * FIN + fl);
            unpack2(r.x, x0, x1);
            unpack2(r.y, x2, x3);
            float4 q = qs[k];
            acc0.x += q.x * x0; acc0.y += q.x * x1; acc0.z += q.x * x2; acc0.w += q.x * x3;
            acc1.x += q.y * x0; acc1.y += q.y * x1; acc1.z += q.y * x2; acc1.w += q.y * x3;
            acc2.x += q.z * x0; acc2.y += q.z * x1; acc2.z += q.z * x2; acc2.w += q.z * x3;
            acc3.x += q.w * x0; acc3.y += q.w * x1; acc3.z += q.w * x2; acc3.w += q.w * x3;
        }
    }

    // ---- stage z into LDS ztile (overwrites qs region) ----
    __syncthreads();
    {
        float* zr = ztile + nloc * ZK;
        *(float4*)(zr + 0 * FIN + fl) = acc0;
        *(float4*)(zr + 1 * FIN + fl) = acc1;
        *(float4*)(zr + 2 * FIN + fl) = acc2;
        *(float4*)(zr + 3 * FIN + fl) = acc3;
    }
    __syncthreads();

    // ---- phase B: in-LDS GEMM ----
    constexpr int OQ  = FOUT / 4;            // quad-outputs per node
    constexpr int QPT = (NPB * OQ) / 256;    // 1 (conv1) or 2 (conv2)
    #pragma unroll
    for (int rq = 0; rq < QPT; rq++) {
        int idx = tid + 256 * rq;
        int j   = idx / OQ;
        int o4  = idx - j * OQ;
        float4 acc = *(const float4*)(b + 4 * o4);
        const float* zr = ztile + j * ZK;
        #pragma unroll 4
        for (int kq = 0; kq < K / 4; kq++) {
            float4 zt = *(const float4*)(zr + 4 * kq);
            #pragma unroll
            for (int jj = 0; jj < 4; jj++) {
                float4 wv = *(const float4*)(Ws + (4 * kq + jj) * FOUT + 4 * o4);
                float s = (&zt.x)[jj];
                acc.x += s * wv.x;
                acc.y += s * wv.y;
                acc.z += s * wv.z;
                acc.w += s * wv.w;
            }
        }
        acc.x = fmaxf(acc.x, 0.0f);
        acc.y = fmaxf(acc.y, 0.0f);
        acc.z = fmaxf(acc.z, 0.0f);
        acc.w = fmaxf(acc.w, 0.0f);
        float* hr = hout + j * HS + 4 * o4;
        hr[0] = acc.x; hr[1] = acc.y; hr[2] = acc.z; hr[3] = acc.w;
        int nn = n0 + j;
        if (nn < N_NODES) {
            if (OUT_FP8) {
                unsigned pk = (unsigned)f2fp8(acc.x) | ((unsigned)f2fp8(acc.y) << 8) |
                              ((unsigned)f2fp8(acc.z) << 16) | ((unsigned)f2fp8(acc.w) << 24);
                *(unsigned*)(out_f8 + (size_t)nn * FOUT + 4 * o4) = pk;
            } else {
                ushort4 u;
                u.x = f2bf(acc.x); u.y = f2bf(acc.y); u.z = f2bf(acc.z); u.w = f2bf(acc.w);
                *(ushort4*)(out_bf + (size_t)nn * FOUT + 4 * o4) = u;
            }
        }
    }

    // ---- p_next = hout @ Unext ----
    __syncthreads();
    if (tid < NPB) {
        int nn = n0 + tid;
        if (nn < N_NODES) {
            float a0 = 0, a1 = 0, a2 = 0, a3 = 0;
            const float* hr = hout + tid * HS;
            #pragma unroll
            for (int ff = 0; ff < FOUT; ff++) {
                float xv = hr[ff];
                a0 += xv * Uloc[ff * 4 + 0];
                a1 += xv * Uloc[ff * 4 + 1];
                a2 += xv * Uloc[ff * 4 + 2];
                a3 += xv * Uloc[ff * 4 + 3];
            }
            *(float4*)(pnext + (size_t)nn * 4) = make_float4(a0, a1, a2, a3);
        }
    }
}

// ---------------- zgather v5 (conv3, fp8 in), z out bf16 ----------------

template<int FIN>
__global__ __launch_bounds__(256) void zgather_kernel(
        const int* __restrict__ rowptr, const int* __restrict__ csr_src,
        const float* __restrict__ p, const float* __restrict__ cvec,
        const uchar_t* __restrict__ hf8,  // [N, FIN] fp8
        ushort_t* __restrict__ z)         // [N, 4*FIN] bf16
{
    constexpr int LPN   = FIN / 4;
    constexpr int NPB   = 256 / LPN;
    constexpr int CHUNK = 1024;
    __shared__ int    sbeg[NPB + 1];
    __shared__ float4 pds[NPB];
    __shared__ float4 qs[CHUNK];
    __shared__ int    ssrc[CHUNK];

    int tid  = threadIdx.x;
    int nloc = tid / LPN;
    int fl   = (tid - nloc * LPN) * 4;
    int n0   = blockIdx.x * NPB;
    int n    = n0 + nloc;
    int dbase = n0 & 255;

    for (int i = tid; i <= NPB; i += 256) {
        int idx = n0 + i;
        sbeg[i] = rowptr[idx > N_NODES ? N_NODES : idx];
    }
    for (int i = tid; i < NPB; i += 256) {
        int idx = n0 + i;
        pds[i] = *(const float4*)(p + (size_t)(idx < N_NODES ? idx : N_NODES - 1) * 4);
    }
    float c0 = cvec[0], c1 = cvec[1], c2 = cvec[2], c3 = cvec[3];
    __syncthreads();

    int BB = sbeg[0], BE = sbeg[NPB];
    int beg = sbeg[nloc], end = sbeg[nloc + 1];

    float4 acc0 = make_float4(0, 0, 0, 0), acc1 = acc0, acc2 = acc0, acc3 = acc0;

    for (int cbase = BB; cbase < BE; cbase += CHUNK) {
        int cend = min(cbase + CHUNK, BE);
        __syncthreads();
        for (int k = cbase + tid; k < cend; k += 256) {
            int pk = csr_src[k];
            int s  = pk & ((1 << 20) - 1);
            int nl = (pk >> 20) - dbase;
            float4 ps = *(const float4*)(p + (size_t)s * 4);
            float4 pd = pds[nl];
            float l0 = ps.x - pd.x + c0;
            float l1 = ps.y - pd.y + c1;
            float l2 = ps.z - pd.z + c2;
            float l3 = ps.w - pd.w + c3;
            float m  = fmaxf(fmaxf(l0, l1), fmaxf(l2, l3));
            float e0 = __expf(l0 - m), e1 = __expf(l1 - m);
            float e2 = __expf(l2 - m), e3 = __expf(l3 - m);
            float deg = (float)(sbeg[nl + 1] - sbeg[nl]);
            float inv = 1.0f / (fmaxf(deg, 1.0f) * (e0 + e1 + e2 + e3));
            qs[k - cbase]   = make_float4(e0 * inv, e1 * inv, e2 * inv, e3 * inv);
            ssrc[k - cbase] = s;
        }
        __syncthreads();
        int kb = (beg > cbase ? beg : cbase) - cbase;
        int ke = (end < cend ? end : cend) - cbase;
        int k = kb;
        for (; k + 4 <= ke; k += 4) {
            unsigned r[4];
            #pragma unroll
            for (int j = 0; j < 4; j++)
                r[j] = *(const unsigned*)(hf8 + (size_t)ssrc[k + j] * FIN + fl);
            float xv[4][4];
            #pragma unroll
            for (int j = 0; j < 4; j++) {
                xv[j][0] = fp8d((uchar_t)(r[j] & 255));
                xv[j][1] = fp8d((uchar_t)((r[j] >> 8) & 255));
                xv[j][2] = fp8d((uchar_t)((r[j] >> 16) & 255));
                xv[j][3] = fp8d((uchar_t)(r[j] >> 24));
            }
            #pragma unroll
            for (int j = 0; j < 4; j++) {
                float4 q = qs[k + j];
                acc0.x += q.x * xv[j][0]; acc0.y += q.x * xv[j][1];
                acc0.z += q.x * xv[j][2]; acc0.w += q.x * xv[j][3];
                acc1.x += q.y * xv[j][0]; acc1.y += q.y * xv[j][1];
                acc1.z += q.y * xv[j][2]; acc1.w += q.y * xv[j][3];
                acc2.x += q.z * xv[j][0]; acc2.y += q.z * xv[j][1];
                acc2.z += q.z * xv[j][2]; acc2.w += q.z * xv[j][3];
                acc3.x += q.w * xv[j][0]; acc3.y += q.w * xv[j][1];
                acc3.z += q.w * xv[j][2]; acc3.w += q.w * xv[j][3];
            }
        }
        for (; k < ke; k++) {
            unsigned r = *(const unsigned*)(hf8 + (size_t)ssrc[k] * FIN + fl);
            float x0 = fp8d((uchar_t)(r & 255));
            float x1 = fp8d((uchar_t)((r >> 8) & 255));
            float x2 = fp8d((uchar_t)((r >> 16) & 255));
            float x3 = fp8d((uchar_t)(r >> 24));
            float4 q = qs[k];
            acc0.x += q.x * x0; acc0.y += q.x * x1; acc0.z += q.x * x2; acc0.w += q.x * x3;
            acc1.x += q.y * x0; acc1.y += q.y * x1; acc1.z += q.y * x2; acc1.w += q.y * x3;
            acc2.x += q.z * x0; acc2.y += q.z * x1; acc2.z += q.z * x2; acc2.w += q.z * x3;
            acc3.x += q.w * x0; acc3.y += q.w * x1; acc3.z += q.w * x2; acc3.w += q.w * x3;
        }
    }

    if (n < N_NODES) {
        size_t base = (size_t)n * (4 * FIN) + fl;
        ushort4 u;
        u.x = f2bf(acc0.x); u.y = f2bf(acc0.y); u.z = f2bf(acc0.z); u.w = f2bf(acc0.w);
        *(ushort4*)(z + base) = u;
        u.x = f2bf(acc1.x); u.y = f2bf(acc1.y); u.z = f2bf(acc1.z); u.w = f2bf(acc1.w);
        *(ushort4*)(z + base + FIN) = u;
        u.x = f2bf(acc2.x); u.y = f2bf(acc2.y); u.z = f2bf(acc2.z); u.w = f2bf(acc2.w);
        *(ushort4*)(z + base + 2 * FIN) = u;
        u.x = f2bf(acc3.x); u.y = f2bf(acc3.y); u.z = f2bf(acc3.z); u.w = f2bf(acc3.w);
        *(ushort4*)(z + base + 3 * FIN) = u;
    }
}

// ---------------- post3 + fused tail: z(bf16) -> h3 (LDS htile) -> MLP -> sigmoid ----

__global__ __launch_bounds__(256, 2) void post_tail_kernel(
        const ushort_t* __restrict__ z,   // [N, 128] bf16
        const float* __restrict__ W,      // [32, 256]
        const float* __restrict__ b,      // [64]
        const float* __restrict__ lw1, const float* __restrict__ lb1,
        const float* __restrict__ lw2, const float* __restrict__ lb2,
        const float* __restrict__ lw3, const float* __restrict__ lb3,
        const float* __restrict__ lw4, const float* __restrict__ lb4,
        const float* __restrict__ lw5, const float* __restrict__ lb5,
        float* __restrict__ out)
{
    constexpr int FIN = 32, FOUT = 64;
    constexpr int K   = 4 * FIN;          // 128
    constexpr int OL  = FOUT / 4;         // 16
    constexpr int NPB = 4 * (256 / OL);   // 64 nodes/block
    constexpr int WSZ = FIN * 4 * FOUT;   // 8192
    constexpr int HS  = 65;               // htile stride (scalar stores, conflict-free)
    __shared__ float Wp[WSZ];             // 32 KB
    __shared__ float htile[NPB * HS];     // 16.6 KB
    __shared__ float w1[64 * 32], w2[32 * 16], w3[16 * 8], w4[8 * 4], w5[4];
    __shared__ float B1[32], B2[16], B3[8], B4[4], B5[1];

    int tid = threadIdx.x;
    for (int i = tid; i < WSZ; i += 256) {
        int f = i / (4 * FOUT);
        int r = i - f * (4 * FOUT);
        int h = r / FOUT;
        int o = r - h * FOUT;
        Wp[(h * FIN + f) * FOUT + o] = W[i];
    }
    for (int i = tid; i < 64 * 32; i += 256) w1[i] = lw1[i];
    for (int i = tid; i < 32 * 16; i += 256) w2[i] = lw2[i];
    for (int i = tid; i < 16 * 8;  i += 256) w3[i] = lw3[i];
    for (int i = tid; i < 8 * 4;   i += 256) w4[i] = lw4[i];
    for (int i = tid; i < 4;       i += 256) w5[i] = lw5[i];
    for (int i = tid; i < 32; i += 256) B1[i] = lb1[i];
    for (int i = tid; i < 16; i += 256) B2[i] = lb2[i];
    for (int i = tid; i < 8;  i += 256) B3[i] = lb3[i];
    for (int i = tid; i < 4;  i += 256) B4[i] = lb4[i];
    if (tid == 0) B5[0] = lb5[0];
    __syncthreads();

    int ol = tid % OL;
    int g  = tid / OL;
    int n0 = blockIdx.x * NPB + g * 4;

    float4 bv = *(const float4*)(b + 4 * ol);
    float4 acc[4];
    const ushort_t* zr[4];
    #pragma unroll
    for (int j = 0; j < 4; j++) {
        acc[j] = make_float4(0.f, 0.f, 0.f, 0.f);
        int nn = n0 + j; if (nn > N_NODES - 1) nn = N_NODES - 1;
        zr[j] = z + (size_t)nn * K;
    }

    #pragma unroll 2
    for (int kq = 0; kq < K / 4; kq++) {
        float zv[4][4];
        #pragma unroll
        for (int j = 0; j < 4; j++) {
            ushort4 zu = *(const ushort4*)(zr[j] + 4 * kq);
            zv[j][0] = bf2f(zu.x); zv[j][1] = bf2f(zu.y);
            zv[j][2] = bf2f(zu.z); zv[j][3] = bf2f(zu.w);
        }
        #pragma unroll
        for (int jj = 0; jj < 4; jj++) {
            float4 wv = *(const float4*)(Wp + (4 * kq + jj) * FOUT + 4 * ol);
            #pragma unroll
            for (int j = 0; j < 4; j++) {
                float s = zv[j][jj];
                acc[j].x += s * wv.x;
                acc[j].y += s * wv.y;
                acc[j].z += s * wv.z;
                acc[j].w += s * wv.w;
            }
        }
    }

    #pragma unroll
    for (int j = 0; j < 4; j++) {
        float* hr = htile + (g * 4 + j) * HS + 4 * ol;
        hr[0] = fmaxf(acc[j].x + bv.x, 0.0f);
        hr[1] = fmaxf(acc[j].y + bv.y, 0.0f);
        hr[2] = fmaxf(acc[j].z + bv.z, 0.0f);
        hr[3] = fmaxf(acc[j].w + bv.w, 0.0f);
    }
    __syncthreads();

    // ---- tail: one thread per node ----
    if (tid < NPB) {
        int nn = blockIdx.x * NPB + tid;
        if (nn < N_NODES) {
            const float* a = htile + tid * HS;
            float t1[32];
            for (int o = 0; o < 32; o++) {
                float s = B1[o];
                #pragma unroll 8
                for (int i = 0; i < 64; i++) s += a[i] * w1[i * 32 + o];
                t1[o] = fmaxf(s, 0.0f);
            }
            float t2[16];
            for (int o = 0; o < 16; o++) {
                float s = B2[o];
                #pragma unroll
                for (int i = 0; i < 32; i++) s += t1[i] * w2[i * 16 + o];
                t2[o] = fmaxf(s, 0.0f);
            }
            float t3[8];
            for (int o = 0; o < 8; o++) {
                float s = B3[o];
                #pragma unroll
                for (int i = 0; i < 16; i++) s += t2[i] * w3[i * 8 + o];
                t3[o] = fmaxf(s, 0.0f);
            }
            float t4[4];
            for (int o = 0; o < 4; o++) {
                float s = B4[o];
                #pragma unroll
                for (int i = 0; i < 8; i++) s += t3[i] * w4[i * 4 + o];
                t4[o] = fmaxf(s, 0.0f);
            }
            float zf = B5[0];
            #pragma unroll
            for (int i = 0; i < 4; i++) zf += t4[i] * w5[i];
            out[nn] = 1.0f / (1.0f + expf(-zf));
        }
    }
}

// ---------------- host launch ----------------

extern "C" void kernel_launch(void* const* d_in, const int* in_sizes, int n_in,
                              void* d_out, int out_size, void* d_ws, size_t ws_size,
                              hipStream_t stream) {
    const float* x   = (const float*)d_in[0];
    const int*   ei  = (const int*)d_in[1];
    const int*   src = ei;
    const int*   dst = ei + N_EDGES;
    const float* U1 = (const float*)d_in[2];  const float* c1 = (const float*)d_in[3];
    const float* W1 = (const float*)d_in[4];  const float* b1 = (const float*)d_in[5];
    const float* U2 = (const float*)d_in[6];  const float* c2 = (const float*)d_in[7];
    const float* W2 = (const float*)d_in[8];  const float* b2 = (const float*)d_in[9];
    const float* U3 = (const float*)d_in[10]; const float* c3 = (const float*)d_in[11];
    const float* W3 = (const float*)d_in[12]; const float* b3 = (const float*)d_in[13];
    const float* lw1 = (const float*)d_in[14]; const float* lb1 = (const float*)d_in[15];
    const float* lw2 = (const float*)d_in[16]; const float* lb2 = (const float*)d_in[17];
    const float* lw3 = (const float*)d_in[18]; const float* lb3 = (const float*)d_in[19];
    const float* lw4 = (const float*)d_in[20]; const float* lb4 = (const float*)d_in[21];
    const float* lw5 = (const float*)d_in[22]; const float* lb5 = (const float*)d_in[23];

    char* ws = (char*)d_ws;
    size_t off = 0;
    auto alloc = [&](size_t bytes) -> void* {
        void* ptr = (void*)(ws + off);
        off += (bytes + 255) & ~(size_t)255;
        return ptr;
    };
    int*      hist_rows     = (int*)alloc((size_t)NCHUNK * NBKT * 4);
    int*      bucket_cnt    = (int*)alloc((size_t)(NBKT + 1) * 4);
    int*      bucket_base   = (int*)alloc((size_t)(NBKT + 1) * 4);
    int*      bucket_cursor = (int*)alloc((size_t)NBKT * 4);
    int*      csr_tmp       = (int*)alloc((size_t)N_EDGES * 4);
    int*      rowptr        = (int*)alloc(((size_t)N_NODES + 1) * 4);
    int*      csr_src       = (int*)alloc((size_t)N_EDGES * 4);
    float*    p             = (float*)alloc((size_t)N_NODES * 4 * 4);
    ushort_t* z             = (ushort_t*)alloc((size_t)N_NODES * 128 * 2);
    ushort_t* xbf           = (ushort_t*)alloc((size_t)N_NODES * 16 * 2);
    ushort_t* h1bf          = (ushort_t*)alloc((size_t)N_NODES * 16 * 2);
    uchar_t*  h2f8          = (uchar_t*)alloc((size_t)N_NODES * 32);
    (void)ws_size;

    const int B = 256;

    // ---- CSR build ----
    bhist_pcast_kernel<<<NCHUNK + GN + 1, B, 0, stream>>>(dst, hist_rows, x, U1, p, xbf,
                                                          bucket_cnt);
    ksum_kernel<<<NRB, B, 0, stream>>>(hist_rows, bucket_cnt);
    bscan_kernel<<<1, 512, 0, stream>>>(bucket_cnt, bucket_base, bucket_cursor);
    partition_kernel<<<NCHUNK, B, 0, stream>>>(src, dst, bucket_cursor, csr_tmp);
    bucket_build_kernel<<<NBKT, B, 0, stream>>>(bucket_base, csr_tmp, rowptr, csr_src);

    const int ZG16 = (N_NODES + 63) / 64;    // 1563 (NPB=64)
    const int ZG32 = (N_NODES + 31) / 32;    // 3125 (NPB=32)
    const int PT   = (N_NODES + 63) / 64;    // post_tail blocks

    // ---- conv1 fused: gather(xbf) + GEMM(W1) -> bf16 h1 + p2 ----
    conv_fused_kernel<16, 16, 0><<<ZG16, B, 0, stream>>>(
        rowptr, csr_src, p, c1, xbf, W1, b1, h1bf, nullptr, U2, p);

    // ---- conv2 fused: gather(h1bf) + GEMM(W2) -> fp8 h2 + p3 ----
    conv_fused_kernel<16, 32, 1><<<ZG16, B, 0, stream>>>(
        rowptr, csr_src, p, c2, h1bf, W2, b2, nullptr, h2f8, U3, p);

    // ---- conv3: fp8 gather -> z(bf16); post3+tail fused -> sigmoid out ----
    zgather_kernel<32><<<ZG32, B, 0, stream>>>(rowptr, csr_src, p, c3, h2f8, z);
    post_tail_kernel<<<PT, B, 0, stream>>>(z, W3, b3, lw1, lb1, lw2, lb2, lw3, lb3,
                                           lw4, lb4, lw5, lb5, (float*)d_out);
}

// Round 18
// 320.655 us; speedup vs baseline: 1.2174x; 1.2174x over previous
//
#include <hip/hip_runtime.h>
#include <math.h>

#define N_NODES 100000
#define N_EDGES 1600000
#define HEADS 4
#define NBKT ((N_NODES + 255) / 256)
#define CHUNK_E 4096
#define NCHUNK ((N_EDGES + CHUNK_E - 1) / CHUNK_E)
#define GN ((N_NODES + 255) / 256)
#define SUM_ROWS 16
#define NRB ((NCHUNK + SUM_ROWS - 1) / SUM_ROWS)

typedef unsigned short ushort_t;
typedef unsigned char  uchar_t;

__device__ __forceinline__ ushort_t f2bf(float x) {
    unsigned u = __float_as_uint(x);
    u += 0x7FFF + ((u >> 16) & 1);
    return (ushort_t)(u >> 16);
}
__device__ __forceinline__ float bf2f(ushort_t v) {
    return __uint_as_float(((unsigned)v) << 16);
}
__device__ __forceinline__ void unpack2(unsigned u, float& lo, float& hi) {
    lo = __uint_as_float(u << 16);
    hi = __uint_as_float(u & 0xffff0000u);
}
// unsigned e5m3 fp8 (ReLU outputs only)
__device__ __forceinline__ uchar_t f2fp8(float x) {
    if (x <= 0.0f) return 0;
    unsigned u = __float_as_uint(x) + (1u << 19);
    int e = (int)(u >> 23) - 127 + 15;
    if (e <= 0) return 0;
    if (e > 31) return (uchar_t)255;
    return (uchar_t)((e << 3) | ((u >> 20) & 7));
}
__device__ __forceinline__ float fp8d(uchar_t b) {
    unsigned v = (((unsigned)(b >> 3) + 112u) << 23) | ((unsigned)(b & 7) << 20);
    return (b == 0) ? 0.0f : __uint_as_float(v);
}

// ---------------- K1: per-chunk histogram rows + p1/x->bf16 + bucket_cnt zero ----

__global__ __launch_bounds__(256) void bhist_pcast_kernel(
        const int* __restrict__ dst, int* __restrict__ hist_rows,
        const float* __restrict__ x, const float* __restrict__ U,
        float* __restrict__ p, ushort_t* __restrict__ xbf,
        int* __restrict__ bucket_cnt)
{
    __shared__ int h[NBKT];
    if (blockIdx.x < NCHUNK) {
        for (int i = threadIdx.x; i < NBKT; i += 256) h[i] = 0;
        __syncthreads();
        int base = blockIdx.x * CHUNK_E;
        #pragma unroll
        for (int j = 0; j < CHUNK_E / 256; j++) {
            int e = base + j * 256 + threadIdx.x;
            if (e < N_EDGES) atomicAdd(&h[dst[e] >> 8], 1);
        }
        __syncthreads();
        for (int i = threadIdx.x; i < NBKT; i += 256)
            hist_rows[(size_t)blockIdx.x * NBKT + i] = h[i];
    } else if (blockIdx.x < NCHUNK + GN) {
        int n = (blockIdx.x - NCHUNK) * 256 + threadIdx.x;
        if (n >= N_NODES) return;
        float a0 = 0, a1 = 0, a2 = 0, a3 = 0;
        const float* hr = x + (size_t)n * 16;
        float xv[16];
        #pragma unroll
        for (int f = 0; f < 16; f++) {
            xv[f] = hr[f];
            a0 += xv[f] * U[f * 4 + 0];
            a1 += xv[f] * U[f * 4 + 1];
            a2 += xv[f] * U[f * 4 + 2];
            a3 += xv[f] * U[f * 4 + 3];
        }
        *(float4*)(p + (size_t)n * 4) = make_float4(a0, a1, a2, a3);
        #pragma unroll
        for (int j = 0; j < 4; j++) {
            ushort4 u;
            u.x = f2bf(xv[4 * j + 0]); u.y = f2bf(xv[4 * j + 1]);
            u.z = f2bf(xv[4 * j + 2]); u.w = f2bf(xv[4 * j + 3]);
            *(ushort4*)(xbf + (size_t)n * 16 + 4 * j) = u;
        }
    } else {
        for (int i = threadIdx.x; i < NBKT; i += 256) bucket_cnt[i] = 0;
    }
}

// ---------------- K2a: parallel column-sum ----

__global__ __launch_bounds__(256) void ksum_kernel(const int* __restrict__ hist_rows,
                                                   int* __restrict__ bucket_cnt) {
    int r0 = blockIdx.x * SUM_ROWS;
    int r1 = min(r0 + SUM_ROWS, NCHUNK);
    for (int i = threadIdx.x; i < NBKT; i += 256) {
        int v = 0;
        for (int r = r0; r < r1; r++) v += hist_rows[(size_t)r * NBKT + i];
        if (v) atomicAdd(&bucket_cnt[i], v);
    }
}

// ---------------- K2b: exclusive scan -> base + cursor ----

__global__ __launch_bounds__(512) void bscan_kernel(const int* __restrict__ bucket_cnt,
                                                    int* __restrict__ bucket_base,
                                                    int* __restrict__ bucket_cursor) {
    __shared__ int tmp[512];
    int i = threadIdx.x;
    int v = (i < NBKT) ? bucket_cnt[i] : 0;
    tmp[i] = v;
    __syncthreads();
    for (int off = 1; off < 512; off <<= 1) {
        int t = (i >= off) ? tmp[i - off] : 0;
        __syncthreads();
        tmp[i] += t;
        __syncthreads();
    }
    int excl = tmp[i] - v;
    if (i < NBKT) { bucket_base[i] = excl; bucket_cursor[i] = excl; }
    if (i == NBKT) bucket_base[NBKT] = N_EDGES;
}

// ---------------- K3: partition into coarse buckets; packed = (dst&255)<<20 | src ----

__global__ __launch_bounds__(256) void partition_kernel(const int* __restrict__ src,
                                                        const int* __restrict__ dst,
                                                        int* __restrict__ bucket_cursor,
                                                        int* __restrict__ csr_tmp) {
    constexpr int EPT = CHUNK_E / 256;
    __shared__ int h[NBKT];
    __shared__ int gbase[NBKT];
    __shared__ int rcnt[NBKT];
    for (int i = threadIdx.x; i < NBKT; i += 256) { h[i] = 0; rcnt[i] = 0; }
    __syncthreads();
    int base = blockIdx.x * CHUNK_E;
    int d[EPT], s[EPT];
    #pragma unroll
    for (int j = 0; j < EPT; j++) {
        int e = base + j * 256 + threadIdx.x;
        d[j] = (e < N_EDGES) ? dst[e] : -1;
        s[j] = (e < N_EDGES) ? src[e] : 0;
        if (d[j] >= 0) atomicAdd(&h[d[j] >> 8], 1);
    }
    __syncthreads();
    for (int i = threadIdx.x; i < NBKT; i += 256)
        if (h[i]) gbase[i] = atomicAdd(&bucket_cursor[i], h[i]);
    __syncthreads();
    #pragma unroll
    for (int j = 0; j < EPT; j++) {
        if (d[j] >= 0) {
            int b = d[j] >> 8;
            int r = atomicAdd(&rcnt[b], 1);
            csr_tmp[gbase[b] + r] = ((d[j] & 255) << 20) | s[j];
        }
    }
}

// ---------------- K4: per-bucket build; csr_src keeps dlow packed ----

__global__ __launch_bounds__(256) void bucket_build_kernel(const int* __restrict__ bucket_base,
                                                           const int* __restrict__ csr_tmp,
                                                           int* __restrict__ rowptr,
                                                           int* __restrict__ csr_src) {
    __shared__ int cnt[256];
    __shared__ int tscan[256];
    __shared__ int exc[256];
    __shared__ int stage[8192];
    int b = blockIdx.x;
    int rbeg = bucket_base[b], rend = bucket_base[b + 1];
    int sz = rend - rbeg;
    int tid = threadIdx.x;

    cnt[tid] = 0;
    __syncthreads();
    for (int k = rbeg + tid; k < rend; k += 256) atomicAdd(&cnt[csr_tmp[k] >> 20], 1);
    __syncthreads();
    int v = cnt[tid];
    tscan[tid] = v;
    __syncthreads();
    for (int off = 1; off < 256; off <<= 1) {
        int t = (tid >= off) ? tscan[tid - off] : 0;
        __syncthreads();
        tscan[tid] += t;
        __syncthreads();
    }
    int ex = tscan[tid] - v;
    int node = b * 256 + tid;
    if (node < N_NODES) rowptr[node] = rbeg + ex;
    if (b == 0 && tid == 0) rowptr[N_NODES] = N_EDGES;
    exc[tid] = ex;
    cnt[tid] = 0;
    __syncthreads();

    if (sz <= 8192) {
        for (int k = rbeg + tid; k < rend; k += 256) {
            int pk = csr_tmp[k];
            int dl = pk >> 20;
            int r  = atomicAdd(&cnt[dl], 1);
            stage[exc[dl] + r] = pk;
        }
        __syncthreads();
        for (int i = tid; i < sz; i += 256) csr_src[rbeg + i] = stage[i];
    } else {
        for (int k = rbeg + tid; k < rend; k += 256) {
            int pk = csr_tmp[k];
            int dl = pk >> 20;
            int r  = atomicAdd(&cnt[dl], 1);
            csr_src[rbeg + exc[dl] + r] = pk;
        }
    }
}

// ---------------- fused conv (conv1/conv2): gather -> LDS ztile -> in-LDS GEMM
// -> bf16/fp8 out + p_next.  W LDS-resident, amortized over NPB=64 nodes.

template<int FIN, int FOUT, int OUT_FP8>
__global__ __launch_bounds__(256) void conv_fused_kernel(
        const int* __restrict__ rowptr, const int* __restrict__ csr_src,
        const float* __restrict__ p, const float* __restrict__ cvec,
        const ushort_t* __restrict__ hprev,   // [N, FIN] bf16
        const float* __restrict__ W,          // [FIN, 4*FOUT]
        const float* __restrict__ b,          // [FOUT]
        ushort_t* __restrict__ out_bf,        // [N, FOUT] (OUT_FP8==0)
        uchar_t* __restrict__ out_f8,         // [N, FOUT] (OUT_FP8==1)
        const float* __restrict__ Unext,      // [FOUT,4]
        float* __restrict__ pnext)            // [N,4]
{
    constexpr int LPN   = FIN / 4;            // 4
    constexpr int NPB   = 256 / LPN;          // 64
    constexpr int CHUNK = 1024;
    constexpr int K     = 4 * FIN;            // 64
    constexpr int ZK    = K + 4;
    constexpr int HS    = FOUT + 1;
    constexpr int WSZ   = K * FOUT;
    constexpr int UNION_A = CHUNK * 16 + CHUNK * 4;
    constexpr int UNION_B = NPB * ZK * 4 + NPB * HS * 4;
    constexpr int UNION   = UNION_A > UNION_B ? UNION_A : UNION_B;

    __shared__ int    sbeg[NPB + 1];
    __shared__ float4 pds[NPB];
    __shared__ float  Ws[WSZ];
    __shared__ float  Uloc[FOUT * 4];
    __shared__ __align__(16) char ubuf[UNION];
    float4* qs    = (float4*)ubuf;
    int*    ssrc  = (int*)(ubuf + CHUNK * 16);
    float*  ztile = (float*)ubuf;
    float*  hout  = (float*)(ubuf + NPB * ZK * 4);

    int tid  = threadIdx.x;
    int nloc = tid / LPN;
    int fl   = (tid - nloc * LPN) * 4;
    int n0   = blockIdx.x * NPB;
    int n    = n0 + nloc;
    int dbase = n0 & 255;

    for (int i = tid; i <= NPB; i += 256) {
        int idx = n0 + i;
        sbeg[i] = rowptr[idx > N_NODES ? N_NODES : idx];
    }
    for (int i = tid; i < NPB; i += 256) {
        int idx = n0 + i;
        pds[i] = *(const float4*)(p + (size_t)(idx < N_NODES ? idx : N_NODES - 1) * 4);
    }
    for (int i = tid; i < WSZ; i += 256) {
        int f = i / (4 * FOUT);
        int r = i - f * (4 * FOUT);
        int h = r / FOUT;
        int o = r - h * FOUT;
        Ws[(h * FIN + f) * FOUT + o] = W[i];
    }
    for (int i = tid; i < FOUT * 4; i += 256) Uloc[i] = Unext[i];
    float c0 = cvec[0], c1 = cvec[1], c2 = cvec[2], c3 = cvec[3];
    __syncthreads();

    int BB = sbeg[0], BE = sbeg[NPB];
    int beg = sbeg[nloc], end = sbeg[nloc + 1];

    float4 acc0 = make_float4(0, 0, 0, 0), acc1 = acc0, acc2 = acc0, acc3 = acc0;

    for (int cbase = BB; cbase < BE; cbase += CHUNK) {
        int cend = min(cbase + CHUNK, BE);
        __syncthreads();
        for (int k = cbase + tid; k < cend; k += 256) {
            int pk = csr_src[k];
            int s  = pk & ((1 << 20) - 1);
            int nl = (pk >> 20) - dbase;
            float4 ps = *(const float4*)(p + (size_t)s * 4);
            float4 pd = pds[nl];
            float l0 = ps.x - pd.x + c0;
            float l1 = ps.y - pd.y + c1;
            float l2 = ps.z - pd.z + c2;
            float l3 = ps.w - pd.w + c3;
            float m  = fmaxf(fmaxf(l0, l1), fmaxf(l2, l3));
            float e0 = __expf(l0 - m), e1 = __expf(l1 - m);
            float e2 = __expf(l2 - m), e3 = __expf(l3 - m);
            float deg = (float)(sbeg[nl + 1] - sbeg[nl]);
            float inv = 1.0f / (fmaxf(deg, 1.0f) * (e0 + e1 + e2 + e3));
            qs[k - cbase]   = make_float4(e0 * inv, e1 * inv, e2 * inv, e3 * inv);
            ssrc[k - cbase] = s;
        }
        __syncthreads();
        int kb = (beg > cbase ? beg : cbase) - cbase;
        int ke = (end < cend ? end : cend) - cbase;
        int k = kb;
        for (; k + 4 <= ke; k += 4) {
            uint2 r[4];
            #pragma unroll
            for (int j = 0; j < 4; j++)
                r[j] = *(const uint2*)(hprev + (size_t)ssrc[k + j] * FIN + fl);
            float xv[4][4];
            #pragma unroll
            for (int j = 0; j < 4; j++) {
                unpack2(r[j].x, xv[j][0], xv[j][1]);
                unpack2(r[j].y, xv[j][2], xv[j][3]);
            }
            #pragma unroll
            for (int j = 0; j < 4; j++) {
                float4 q = qs[k + j];
                acc0.x += q.x * xv[j][0]; acc0.y += q.x * xv[j][1];
                acc0.z += q.x * xv[j][2]; acc0.w += q.x * xv[j][3];
                acc1.x += q.y * xv[j][0]; acc1.y += q.y * xv[j][1];
                acc1.z += q.y * xv[j][2]; acc1.w += q.y * xv[j][3];
                acc2.x += q.z * xv[j][0]; acc2.y += q.z * xv[j][1];
                acc2.z += q.z * xv[j][2]; acc2.w += q.z * xv[j][3];
                acc3.x += q.w * xv[j][0]; acc3.y += q.w * xv[j][1];
                acc3.z += q.w * xv[j][2]; acc3.w += q.w * xv[j][3];
            }
        }
        for (; k < ke; k++) {
            float x0, x1, x2, x3;
            uint2 r = *(const uint2*)(hprev + (size_t)ssrc[k] * FIN + fl);
            unpack2(r.x, x0, x1);
            unpack2(r.y, x2, x3);
            float4 q = qs[k];
            acc0.x += q.x * x0; acc0.y += q.x * x1; acc0.z += q.x * x2; acc0.w += q.x * x3;
            acc1.x += q.y * x0; acc1.y += q.y * x1; acc1.z += q.y * x2; acc1.w += q.y * x3;
            acc2.x += q.z * x0; acc2.y += q.z * x1; acc2.z += q.z * x2; acc2.w += q.z * x3;
            acc3.x += q.w * x0; acc3.y += q.w * x1; acc3.z += q.w * x2; acc3.w += q.w * x3;
        }
    }

    __syncthreads();
    {
        float* zr = ztile + nloc * ZK;
        *(float4*)(zr + 0 * FIN + fl) = acc0;
        *(float4*)(zr + 1 * FIN + fl) = acc1;
        *(float4*)(zr + 2 * FIN + fl) = acc2;
        *(float4*)(zr + 3 * FIN + fl) = acc3;
    }
    __syncthreads();

    constexpr int OQ  = FOUT / 4;
    constexpr int QPT = (NPB * OQ) / 256;
    #pragma unroll
    for (int rq = 0; rq < QPT; rq++) {
        int idx = tid + 256 * rq;
        int j   = idx / OQ;
        int o4  = idx - j * OQ;
        float4 acc = *(const float4*)(b + 4 * o4);
        const float* zr = ztile + j * ZK;
        #pragma unroll 4
        for (int kq = 0; kq < K / 4; kq++) {
            float4 zt = *(const float4*)(zr + 4 * kq);
            #pragma unroll
            for (int jj = 0; jj < 4; jj++) {
                float4 wv = *(const float4*)(Ws + (4 * kq + jj) * FOUT + 4 * o4);
                float s = (&zt.x)[jj];
                acc.x += s * wv.x;
                acc.y += s * wv.y;
                acc.z += s * wv.z;
                acc.w += s * wv.w;
            }
        }
        acc.x = fmaxf(acc.x, 0.0f);
        acc.y = fmaxf(acc.y, 0.0f);
        acc.z = fmaxf(acc.z, 0.0f);
        acc.w = fmaxf(acc.w, 0.0f);
        float* hr = hout + j * HS + 4 * o4;
        hr[0] = acc.x; hr[1] = acc.y; hr[2] = acc.z; hr[3] = acc.w;
        int nn = n0 + j;
        if (nn < N_NODES) {
            if (OUT_FP8) {
                unsigned pk = (unsigned)f2fp8(acc.x) | ((unsigned)f2fp8(acc.y) << 8) |
                              ((unsigned)f2fp8(acc.z) << 16) | ((unsigned)f2fp8(acc.w) << 24);
                *(unsigned*)(out_f8 + (size_t)nn * FOUT + 4 * o4) = pk;
            } else {
                ushort4 u;
                u.x = f2bf(acc.x); u.y = f2bf(acc.y); u.z = f2bf(acc.z); u.w = f2bf(acc.w);
                *(ushort4*)(out_bf + (size_t)nn * FOUT + 4 * o4) = u;
            }
        }
    }

    __syncthreads();
    if (tid < NPB) {
        int nn = n0 + tid;
        if (nn < N_NODES) {
            float a0 = 0, a1 = 0, a2 = 0, a3 = 0;
            const float* hr = hout + tid * HS;
            #pragma unroll
            for (int ff = 0; ff < FOUT; ff++) {
                float xv = hr[ff];
                a0 += xv * Uloc[ff * 4 + 0];
                a1 += xv * Uloc[ff * 4 + 1];
                a2 += xv * Uloc[ff * 4 + 2];
                a3 += xv * Uloc[ff * 4 + 3];
            }
            *(float4*)(pnext + (size_t)nn * 4) = make_float4(a0, a1, a2, a3);
        }
    }
}

// ---------------- zgather v5 (conv3, fp8 in), z out bf16 ----------------

template<int FIN>
__global__ __launch_bounds__(256) void zgather_kernel(
        const int* __restrict__ rowptr, const int* __restrict__ csr_src,
        const float* __restrict__ p, const float* __restrict__ cvec,
        const uchar_t* __restrict__ hf8,  // [N, FIN] fp8
        ushort_t* __restrict__ z)         // [N, 4*FIN] bf16
{
    constexpr int LPN   = FIN / 4;
    constexpr int NPB   = 256 / LPN;
    constexpr int CHUNK = 1024;
    __shared__ int    sbeg[NPB + 1];
    __shared__ float4 pds[NPB];
    __shared__ float4 qs[CHUNK];
    __shared__ int    ssrc[CHUNK];

    int tid  = threadIdx.x;
    int nloc = tid / LPN;
    int fl   = (tid - nloc * LPN) * 4;
    int n0   = blockIdx.x * NPB;
    int n    = n0 + nloc;
    int dbase = n0 & 255;

    for (int i = tid; i <= NPB; i += 256) {
        int idx = n0 + i;
        sbeg[i] = rowptr[idx > N_NODES ? N_NODES : idx];
    }
    for (int i = tid; i < NPB; i += 256) {
        int idx = n0 + i;
        pds[i] = *(const float4*)(p + (size_t)(idx < N_NODES ? idx : N_NODES - 1) * 4);
    }
    float c0 = cvec[0], c1 = cvec[1], c2 = cvec[2], c3 = cvec[3];
    __syncthreads();

    int BB = sbeg[0], BE = sbeg[NPB];
    int beg = sbeg[nloc], end = sbeg[nloc + 1];

    float4 acc0 = make_float4(0, 0, 0, 0), acc1 = acc0, acc2 = acc0, acc3 = acc0;

    for (int cbase = BB; cbase < BE; cbase += CHUNK) {
        int cend = min(cbase + CHUNK, BE);
        __syncthreads();
        for (int k = cbase + tid; k < cend; k += 256) {
            int pk = csr_src[k];
            int s  = pk & ((1 << 20) - 1);
            int nl = (pk >> 20) - dbase;
            float4 ps = *(const float4*)(p + (size_t)s * 4);
            float4 pd = pds[nl];
            float l0 = ps.x - pd.x + c0;
            float l1 = ps.y - pd.y + c1;
            float l2 = ps.z - pd.z + c2;
            float l3 = ps.w - pd.w + c3;
            float m  = fmaxf(fmaxf(l0, l1), fmaxf(l2, l3));
            float e0 = __expf(l0 - m), e1 = __expf(l1 - m);
            float e2 = __expf(l2 - m), e3 = __expf(l3 - m);
            float deg = (float)(sbeg[nl + 1] - sbeg[nl]);
            float inv = 1.0f / (fmaxf(deg, 1.0f) * (e0 + e1 + e2 + e3));
            qs[k - cbase]   = make_float4(e0 * inv, e1 * inv, e2 * inv, e3 * inv);
            ssrc[k - cbase] = s;
        }
        __syncthreads();
        int kb = (beg > cbase ? beg : cbase) - cbase;
        int ke = (end < cend ? end : cend) - cbase;
        int k = kb;
        for (; k + 4 <= ke; k += 4) {
            unsigned r[4];
            #pragma unroll
            for (int j = 0; j < 4; j++)
                r[j] = *(const unsigned*)(hf8 + (size_t)ssrc[k + j] * FIN + fl);
            float xv[4][4];
            #pragma unroll
            for (int j = 0; j < 4; j++) {
                xv[j][0] = fp8d((uchar_t)(r[j] & 255));
                xv[j][1] = fp8d((uchar_t)((r[j] >> 8) & 255));
                xv[j][2] = fp8d((uchar_t)((r[j] >> 16) & 255));
                xv[j][3] = fp8d((uchar_t)(r[j] >> 24));
            }
            #pragma unroll
            for (int j = 0; j < 4; j++) {
                float4 q = qs[k + j];
                acc0.x += q.x * xv[j][0]; acc0.y += q.x * xv[j][1];
                acc0.z += q.x * xv[j][2]; acc0.w += q.x * xv[j][3];
                acc1.x += q.y * xv[j][0]; acc1.y += q.y * xv[j][1];
                acc1.z += q.y * xv[j][2]; acc1.w += q.y * xv[j][3];
                acc2.x += q.z * xv[j][0]; acc2.y += q.z * xv[j][1];
                acc2.z += q.z * xv[j][2]; acc2.w += q.z * xv[j][3];
                acc3.x += q.w * xv[j][0]; acc3.y += q.w * xv[j][1];
                acc3.z += q.w * xv[j][2]; acc3.w += q.w * xv[j][3];
            }
        }
        for (; k < ke; k++) {
            unsigned r = *(const unsigned*)(hf8 + (size_t)ssrc[k] * FIN + fl);
            float x0 = fp8d((uchar_t)(r & 255));
            float x1 = fp8d((uchar_t)((r >> 8) & 255));
            float x2 = fp8d((uchar_t)((r >> 16) & 255));
            float x3 = fp8d((uchar_t)(r >> 24));
            float4 q = qs[k];
            acc0.x += q.x * x0; acc0.y += q.x * x1; acc0.z += q.x * x2; acc0.w += q.x * x3;
            acc1.x += q.y * x0; acc1.y += q.y * x1; acc1.z += q.y * x2; acc1.w += q.y * x3;
            acc2.x += q.z * x0; acc2.y += q.z * x1; acc2.z += q.z * x2; acc2.w += q.z * x3;
            acc3.x += q.w * x0; acc3.y += q.w * x1; acc3.z += q.w * x2; acc3.w += q.w * x3;
        }
    }

    if (n < N_NODES) {
        size_t base = (size_t)n * (4 * FIN) + fl;
        ushort4 u;
        u.x = f2bf(acc0.x); u.y = f2bf(acc0.y); u.z = f2bf(acc0.z); u.w = f2bf(acc0.w);
        *(ushort4*)(z + base) = u;
        u.x = f2bf(acc1.x); u.y = f2bf(acc1.y); u.z = f2bf(acc1.z); u.w = f2bf(acc1.w);
        *(ushort4*)(z + base + FIN) = u;
        u.x = f2bf(acc2.x); u.y = f2bf(acc2.y); u.z = f2bf(acc2.z); u.w = f2bf(acc2.w);
        *(ushort4*)(z + base + 2 * FIN) = u;
        u.x = f2bf(acc3.x); u.y = f2bf(acc3.y); u.z = f2bf(acc3.z); u.w = f2bf(acc3.w);
        *(ushort4*)(z + base + 3 * FIN) = u;
    }
}

// ---------------- post3: z(bf16) -> bf16 h3 (R16-proven standalone) ----------------

template<int FIN, int FOUT>
__global__ __launch_bounds__(256, 4) void post_kernel(
        const ushort_t* __restrict__ z,   // [N, 4*FIN] bf16
        const float* __restrict__ W,      // [FIN, 4*FOUT]
        const float* __restrict__ b,      // [FOUT]
        ushort_t* __restrict__ out_bf)    // [N, FOUT]
{
    constexpr int K   = 4 * FIN;
    constexpr int OL  = FOUT / 4;
    constexpr int NPB = 4 * (256 / OL);
    constexpr int WSZ = FIN * 4 * FOUT;
    __shared__ float Wp[WSZ];
    for (int i = threadIdx.x; i < WSZ; i += 256) {
        int f = i / (4 * FOUT);
        int r = i - f * (4 * FOUT);
        int h = r / FOUT;
        int o = r - h * FOUT;
        Wp[(h * FIN + f) * FOUT + o] = W[i];
    }
    __syncthreads();

    int ol = threadIdx.x % OL;
    int g  = threadIdx.x / OL;
    int n0 = blockIdx.x * NPB + g * 4;

    float4 bv = *(const float4*)(b + 4 * ol);
    float4 acc[4];
    const ushort_t* zr[4];
    #pragma unroll
    for (int j = 0; j < 4; j++) {
        acc[j] = make_float4(0.f, 0.f, 0.f, 0.f);
        int nn = n0 + j; if (nn > N_NODES - 1) nn = N_NODES - 1;
        zr[j] = z + (size_t)nn * K;
    }

    #pragma unroll 2
    for (int kq = 0; kq < K / 4; kq++) {
        float zv[4][4];
        #pragma unroll
        for (int j = 0; j < 4; j++) {
            ushort4 zu = *(const ushort4*)(zr[j] + 4 * kq);
            zv[j][0] = bf2f(zu.x); zv[j][1] = bf2f(zu.y);
            zv[j][2] = bf2f(zu.z); zv[j][3] = bf2f(zu.w);
        }
        #pragma unroll
        for (int jj = 0; jj < 4; jj++) {
            float4 wv = *(const float4*)(Wp + (4 * kq + jj) * FOUT + 4 * ol);
            #pragma unroll
            for (int j = 0; j < 4; j++) {
                float s = zv[j][jj];
                acc[j].x += s * wv.x;
                acc[j].y += s * wv.y;
                acc[j].z += s * wv.z;
                acc[j].w += s * wv.w;
            }
        }
    }

    #pragma unroll
    for (int j = 0; j < 4; j++) {
        int nn = n0 + j;
        if (nn < N_NODES) {
            ushort4 u;
            u.x = f2bf(fmaxf(acc[j].x + bv.x, 0.0f));
            u.y = f2bf(fmaxf(acc[j].y + bv.y, 0.0f));
            u.z = f2bf(fmaxf(acc[j].z + bv.z, 0.0f));
            u.w = f2bf(fmaxf(acc[j].w + bv.w, 0.0f));
            *(ushort4*)(out_bf + (size_t)nn * FOUT + 4 * ol) = u;
        }
    }
}

// ---------------- fused linear tail (bf16 input): 64->32->16->8->4->1 ----------------

__global__ __launch_bounds__(256) void tail_kernel(
        const ushort_t* __restrict__ h,   // [N, 64] bf16
        const float* __restrict__ lw1, const float* __restrict__ lb1,
        const float* __restrict__ lw2, const float* __restrict__ lb2,
        const float* __restrict__ lw3, const float* __restrict__ lb3,
        const float* __restrict__ lw4, const float* __restrict__ lb4,
        const float* __restrict__ lw5, const float* __restrict__ lb5,
        float* __restrict__ out)
{
    __shared__ float w1[64 * 32], w2[32 * 16], w3[16 * 8], w4[8 * 4], w5[4];
    __shared__ float B1[32], B2[16], B3[8], B4[4], B5[1];
    for (int i = threadIdx.x; i < 64 * 32; i += blockDim.x) w1[i] = lw1[i];
    for (int i = threadIdx.x; i < 32 * 16; i += blockDim.x) w2[i] = lw2[i];
    for (int i = threadIdx.x; i < 16 * 8;  i += blockDim.x) w3[i] = lw3[i];
    for (int i = threadIdx.x; i < 8 * 4;   i += blockDim.x) w4[i] = lw4[i];
    for (int i = threadIdx.x; i < 4;       i += blockDim.x) w5[i] = lw5[i];
    for (int i = threadIdx.x; i < 32; i += blockDim.x) B1[i] = lb1[i];
    for (int i = threadIdx.x; i < 16; i += blockDim.x) B2[i] = lb2[i];
    for (int i = threadIdx.x; i < 8;  i += blockDim.x) B3[i] = lb3[i];
    for (int i = threadIdx.x; i < 4;  i += blockDim.x) B4[i] = lb4[i];
    if (threadIdx.x == 0) B5[0] = lb5[0];
    __syncthreads();

    int n = blockIdx.x * blockDim.x + threadIdx.x;
    if (n >= N_NODES) return;

    float a[64];
    const uint4* hrow = (const uint4*)(h + (size_t)n * 64);
    #pragma unroll
    for (int j = 0; j < 8; j++) {
        uint4 v = hrow[j];
        unpack2(v.x, a[8 * j + 0], a[8 * j + 1]);
        unpack2(v.y, a[8 * j + 2], a[8 * j + 3]);
        unpack2(v.z, a[8 * j + 4], a[8 * j + 5]);
        unpack2(v.w, a[8 * j + 6], a[8 * j + 7]);
    }

    float t1[32];
    for (int o = 0; o < 32; o++) {
        float acc = B1[o];
        #pragma unroll
        for (int i = 0; i < 64; i++) acc += a[i] * w1[i * 32 + o];
        t1[o] = fmaxf(acc, 0.0f);
    }
    float t2[16];
    for (int o = 0; o < 16; o++) {
        float acc = B2[o];
        #pragma unroll
        for (int i = 0; i < 32; i++) acc += t1[i] * w2[i * 16 + o];
        t2[o] = fmaxf(acc, 0.0f);
    }
    float t3[8];
    for (int o = 0; o < 8; o++) {
        float acc = B3[o];
        #pragma unroll
        for (int i = 0; i < 16; i++) acc += t2[i] * w3[i * 8 + o];
        t3[o] = fmaxf(acc, 0.0f);
    }
    float t4[4];
    for (int o = 0; o < 4; o++) {
        float acc = B4[o];
        #pragma unroll
        for (int i = 0; i < 8; i++) acc += t3[i] * w4[i * 4 + o];
        t4[o] = fmaxf(acc, 0.0f);
    }
    float zf = B5[0];
    #pragma unroll
    for (int i = 0; i < 4; i++) zf += t4[i] * w5[i];
    out[n] = 1.0f / (1.0f + expf(-zf));
}

// ---------------- host launch ----------------

extern "C" void kernel_launch(void* const* d_in, const int* in_sizes, int n_in,
                              void* d_out, int out_size, void* d_ws, size_t ws_size,
                              hipStream_t stream) {
    const float* x   = (const float*)d_in[0];
    const int*   ei  = (const int*)d_in[1];
    const int*   src = ei;
    const int*   dst = ei + N_EDGES;
    const float* U1 = (const float*)d_in[2];  const float* c1 = (const float*)d_in[3];
    const float* W1 = (const float*)d_in[4];  const float* b1 = (const float*)d_in[5];
    const float* U2 = (const float*)d_in[6];  const float* c2 = (const float*)d_in[7];
    const float* W2 = (const float*)d_in[8];  const float* b2 = (const float*)d_in[9];
    const float* U3 = (const float*)d_in[10]; const float* c3 = (const float*)d_in[11];
    const float* W3 = (const float*)d_in[12]; const float* b3 = (const float*)d_in[13];
    const float* lw1 = (const float*)d_in[14]; const float* lb1 = (const float*)d_in[15];
    const float* lw2 = (const float*)d_in[16]; const float* lb2 = (const float*)d_in[17];
    const float* lw3 = (const float*)d_in[18]; const float* lb3 = (const float*)d_in[19];
    const float* lw4 = (const float*)d_in[20]; const float* lb4 = (const float*)d_in[21];
    const float* lw5 = (const float*)d_in[22]; const float* lb5 = (const float*)d_in[23];

    char* ws = (char*)d_ws;
    size_t off = 0;
    auto alloc = [&](size_t bytes) -> void* {
        void* ptr = (void*)(ws + off);
        off += (bytes + 255) & ~(size_t)255;
        return ptr;
    };
    int*      hist_rows     = (int*)alloc((size_t)NCHUNK * NBKT * 4);
    int*      bucket_cnt    = (int*)alloc((size_t)(NBKT + 1) * 4);
    int*      bucket_base   = (int*)alloc((size_t)(NBKT + 1) * 4);
    int*      bucket_cursor = (int*)alloc((size_t)NBKT * 4);
    int*      csr_tmp       = (int*)alloc((size_t)N_EDGES * 4);
    int*      rowptr        = (int*)alloc(((size_t)N_NODES + 1) * 4);
    int*      csr_src       = (int*)alloc((size_t)N_EDGES * 4);
    float*    p             = (float*)alloc((size_t)N_NODES * 4 * 4);
    ushort_t* z             = (ushort_t*)alloc((size_t)N_NODES * 128 * 2);
    ushort_t* xbf           = (ushort_t*)alloc((size_t)N_NODES * 16 * 2);
    ushort_t* h1bf          = (ushort_t*)alloc((size_t)N_NODES * 16 * 2);
    uchar_t*  h2f8          = (uchar_t*)alloc((size_t)N_NODES * 32);
    ushort_t* h3bf          = (ushort_t*)alloc((size_t)N_NODES * 64 * 2);
    (void)ws_size;

    const int B = 256;

    // ---- CSR build ----
    bhist_pcast_kernel<<<NCHUNK + GN + 1, B, 0, stream>>>(dst, hist_rows, x, U1, p, xbf,
                                                          bucket_cnt);
    ksum_kernel<<<NRB, B, 0, stream>>>(hist_rows, bucket_cnt);
    bscan_kernel<<<1, 512, 0, stream>>>(bucket_cnt, bucket_base, bucket_cursor);
    partition_kernel<<<NCHUNK, B, 0, stream>>>(src, dst, bucket_cursor, csr_tmp);
    bucket_build_kernel<<<NBKT, B, 0, stream>>>(bucket_base, csr_tmp, rowptr, csr_src);

    const int ZG16 = (N_NODES + 63) / 64;    // 1563 (NPB=64)
    const int ZG32 = (N_NODES + 31) / 32;    // 3125 (NPB=32)
    const int NPB3 = 4 * (256 / (64 / 4));   // 64

    // ---- conv1 fused: gather(xbf) + GEMM(W1) -> bf16 h1 + p2 ----
    conv_fused_kernel<16, 16, 0><<<ZG16, B, 0, stream>>>(
        rowptr, csr_src, p, c1, xbf, W1, b1, h1bf, nullptr, U2, p);

    // ---- conv2 fused: gather(h1bf) + GEMM(W2) -> fp8 h2 + p3 ----
    conv_fused_kernel<16, 32, 1><<<ZG16, B, 0, stream>>>(
        rowptr, csr_src, p, c2, h1bf, W2, b2, nullptr, h2f8, U3, p);

    // ---- conv3: fp8 gather -> z(bf16); post3 -> bf16 h3; tail -> sigmoid ----
    zgather_kernel<32><<<ZG32, B, 0, stream>>>(rowptr, csr_src, p, c3, h2f8, z);
    post_kernel<32, 64><<<(N_NODES + NPB3 - 1) / NPB3, B, 0, stream>>>(z, W3, b3, h3bf);
    tail_kernel<<<GN, B, 0, stream>>>(h3bf, lw1, lb1, lw2, lb2, lw3, lb3,
                                      lw4, lb4, lw5, lb5, (float*)d_out);
}